// Round 4
// baseline (109.271 us; speedup 1.0000x reference)
//
#include <hip/hip_runtime.h>
#include <math.h>

// ws layout (floats):
//   terms: [0, 6144)        512 * 12 floats {Lr,Li, t0r,t0i, t1r,t1i, t2r,t2i, t3r,t3i, pad,pad}
//   ZT:    [8192, +131072)  65536 float2, stage-A output: ZT[t1*256 + l1]
constexpr int WS_TERMS = 0;
constexpr int WS_ZT    = 8192;

// ---------------------------------------------------------------------------
// Kernel 1: per-n setup.  Bc = Vc @ B (complex), terms[n] = {Lambda, a0*b0, a0*b1, a1*b0, a1*b1}
__global__ __launch_bounds__(256) void k_setup(
    const float* __restrict__ Lr, const float* __restrict__ Li,
    const float* __restrict__ pr, const float* __restrict__ pi,
    const float* __restrict__ qr, const float* __restrict__ qi,
    const float* __restrict__ Vr, const float* __restrict__ Vi,
    const float* __restrict__ Ct, const float* __restrict__ Bv,
    float* __restrict__ terms)
{
    __shared__ float red[8];
    int n = blockIdx.x;
    int t = threadIdx.x;
    float b0 = Bv[t], b1 = Bv[t + 256];
    float sr = fmaf(Vr[n*512 + t], b0, Vr[n*512 + t + 256] * b1);
    float si = fmaf(Vi[n*512 + t], b0, Vi[n*512 + t + 256] * b1);
    #pragma unroll
    for (int off = 32; off > 0; off >>= 1) {
        sr += __shfl_down(sr, off, 64);
        si += __shfl_down(si, off, 64);
    }
    if ((t & 63) == 0) { red[(t >> 6)*2] = sr; red[(t >> 6)*2 + 1] = si; }
    __syncthreads();
    if (t == 0) {
        float b0r = red[0] + red[2] + red[4] + red[6];
        float b0i = red[1] + red[3] + red[5] + red[7];
        float a0r = Ct[2*n], a0i = -Ct[2*n+1];   // conj(Ct_c)
        float a1r = qr[n],   a1i = -qi[n];       // conj(q)
        float b1r = pr[n],   b1i = pi[n];        // p
        float* tm = terms + n * 12;
        tm[0]  = Lr[n];                tm[1]  = Li[n];
        tm[2]  = a0r*b0r - a0i*b0i;    tm[3]  = a0r*b0i + a0i*b0r;
        tm[4]  = a0r*b1r - a0i*b1i;    tm[5]  = a0r*b1i + a0i*b1r;
        tm[6]  = a1r*b0r - a1i*b0i;    tm[7]  = a1r*b0i + a1i*b0r;
        tm[8]  = a1r*b1r - a1i*b1i;    tm[9]  = a1r*b1i + a1i*b1r;
        tm[10] = 0.f;                  tm[11] = 0.f;
    }
}

// ---------------------------------------------------------------------------
// Kernel 2 (fused): Cauchy reduction + resolvent + FFT stage A.
// Grid 256 blocks x 1024 threads; block = l1 owns all l = l1 + 256*l2, l2 in [0,256).
// Thread (u = tid&63, chunk = tid>>6 in [0,16)): l2 in {u, u+64, u+128, u+192},
// n in [chunk*32, chunk*32+32).  Each ds_read_b128 triple now feeds 4 l's (92 VALU/3 reads).
// LDS overlay (floats):
//   phase 1-2: terms[6144] @0
//   phase 3-4: part[4][256][9] @0 (9-pad), red[256][9] @9216
//   phase 5-6: xrow float2[256] @0, partA float2[1024] @512
__global__ __launch_bounds__(1024, 4) void k_mainA(
    const float* __restrict__ terms,
    const float* __restrict__ log_step,
    float* __restrict__ ZTf)
{
    __shared__ float buf[11520];   // 45 KB
    int tid = threadIdx.x;
    int l1  = blockIdx.x;

    // ---- stage terms -> LDS (1536 float4, coalesced)
    {
        float4* dst = (float4*)buf;
        const float4* src = (const float4*)terms;
        for (int i = tid; i < 1536; i += 1024) dst[i] = src[i];
    }

    int u     = tid & 63;
    int chunk = tid >> 6;          // wave-uniform

    // ---- per-l params for l = l1+256*(u+64h), h in [0,4): theta_h = theta0 - h*pi/2,
    // derived by EXACT quadrant rotation of one double sincos (bit-equivalent trig).
    double step = exp((double)log_step[0]);
    double t2s  = 2.0 / step;
    double th0  = -6.283185307179586 * ((double)(l1 + 256*u) / 65536.0);
    double sn0, cn0; sincos(th0, &sn0, &cn0);
    float gr[4], gi[4], cr_[4], ci_[4];
    #pragma unroll
    for (int h = 0; h < 4; ++h) {
        double cn = (h==0) ? cn0 : (h==1) ?  sn0 : (h==2) ? -cn0 : -sn0;
        double sn = (h==0) ? sn0 : (h==1) ? -cn0 : (h==2) ? -sn0 :  cn0;
        double A = 1.0 - cn, C = 1.0 + cn, Bm = -sn, D = sn;
        double den = C*C + D*D;
        if (den == 0.0) {
            // exact pole l = L/2 (only l1=0,u=0,h=2): r=0, atRoots=0 (validated r1-r3 behavior)
            gr[h] = 0.f; gi[h] = 3e30f; cr_[h] = 0.f; ci_[h] = 0.f;
        } else {
            double inv = 1.0 / den;
            gr[h]  = (float)(t2s * (A*C + Bm*D) * inv);
            gi[h]  = (float)(t2s * (Bm*C - A*D) * inv);
            cr_[h] = (float)(2.0 * C * inv);
            ci_[h] = (float)(-2.0 * D * inv);
        }
    }
    __syncthreads();

    // ---- Cauchy loop: 32 n from LDS, 4 l's per read triple
    float ac[4][8];
    #pragma unroll
    for (int h = 0; h < 4; ++h)
        #pragma unroll
        for (int c = 0; c < 8; ++c) ac[h][c] = 0.f;

    const float4* t4 = (const float4*)buf + chunk * 32 * 3;
    #pragma unroll 2
    for (int n = 0; n < 32; ++n) {
        float4 Aq = t4[n*3 + 0];   // Lr, Li, t0r, t0i  (broadcast ds_read_b128)
        float4 Bq = t4[n*3 + 1];   // t1r, t1i, t2r, t2i
        float4 Cq = t4[n*3 + 2];   // t3r, t3i, -, -
        #pragma unroll
        for (int h = 0; h < 4; ++h) {
            float dr = gr[h] - Aq.x;
            float di = gi[h] - Aq.y;
            float dd = fmaf(dr, dr, di * di);    // inf near/at pole -> r=0 (safe)
            float iv = __builtin_amdgcn_rcpf(dd);
            float rr = dr * iv;
            float ri = -di * iv;
            ac[h][0] = fmaf(rr, Aq.z, ac[h][0]); ac[h][0] = fmaf(-ri, Aq.w, ac[h][0]);
            ac[h][1] = fmaf(rr, Aq.w, ac[h][1]); ac[h][1] = fmaf( ri, Aq.z, ac[h][1]);
            ac[h][2] = fmaf(rr, Bq.x, ac[h][2]); ac[h][2] = fmaf(-ri, Bq.y, ac[h][2]);
            ac[h][3] = fmaf(rr, Bq.y, ac[h][3]); ac[h][3] = fmaf( ri, Bq.x, ac[h][3]);
            ac[h][4] = fmaf(rr, Bq.z, ac[h][4]); ac[h][4] = fmaf(-ri, Bq.w, ac[h][4]);
            ac[h][5] = fmaf(rr, Bq.w, ac[h][5]); ac[h][5] = fmaf( ri, Bq.z, ac[h][5]);
            ac[h][6] = fmaf(rr, Cq.x, ac[h][6]); ac[h][6] = fmaf(-ri, Cq.y, ac[h][6]);
            ac[h][7] = fmaf(rr, Cq.y, ac[h][7]); ac[h][7] = fmaf( ri, Cq.x, ac[h][7]);
        }
    }
    __syncthreads();   // terms reads done; LDS reusable

    // ---- fold 16 chunks -> 4 planes (plane = chunk&3; round = chunk>>2, 3 writes first)
    {
        int grp = chunk >> 2, pl = chunk & 3;
        for (int r = 3; r >= 0; --r) {
            if (grp == r) {
                #pragma unroll
                for (int h = 0; h < 4; ++h) {
                    float* p = buf + pl * 2304 + (u + 64*h) * 9;
                    if (r == 3) {
                        #pragma unroll
                        for (int c = 0; c < 8; ++c) p[c] = ac[h][c];
                    } else {
                        #pragma unroll
                        for (int c = 0; c < 8; ++c) p[c] += ac[h][c];
                    }
                }
            }
            __syncthreads();
        }
    }

    // ---- stage-1 reduce: 2048 slots (l2*8+c), sum 4 planes -> red @9216
    for (int s = tid; s < 2048; s += 1024) {
        int a = (s >> 3) * 9 + (s & 7);
        float v = buf[a] + buf[2304 + a] + buf[4608 + a] + buf[6912 + a];
        buf[9216 + a] = v;
    }
    __syncthreads();

    // ---- stage-2: atRoots for l2 = tid (tid<256); own params at h = tid>>6 (u = tid&63)
    if (tid < 256) {
        const float* rd = buf + 9216 + tid * 9;
        float s0r = rd[0], s0i = rd[1], s1r = rd[2], s1i = rd[3];
        float s2r = rd[4], s2i = rd[5], s3r = rd[6], s3i = rd[7];
        int h = tid >> 6;
        float e1r = 1.f + s3r, e1i = s3i;
        float eiv = 1.0f / fmaf(e1r, e1r, e1i * e1i);
        float m_r = s1r * s2r - s1i * s2i;
        float m_i = s1r * s2i + s1i * s2r;
        float q_r = (m_r * e1r + m_i * e1i) * eiv;
        float q_i = (m_i * e1r - m_r * e1i) * eiv;
        float u_r = s0r - q_r;
        float u_i = s0i - q_i;
        float at_r = cr_[h] * u_r - ci_[h] * u_i;
        float at_i = cr_[h] * u_i + ci_[h] * u_r;
        ((float2*)buf)[tid] = make_float2(at_r, at_i);   // xrow @0 (planes dead)
    }
    __syncthreads();

    // ---- FFT stage A over l2 (256-pt DFT, 4-way split) + W_L twiddle -> ZT
    {
        int k = tid & 255;    // t1
        int s = tid >> 8;     // l2-chunk
        int m0 = (s * k) & 3;
        float curR = (m0 == 0) ? 1.f : (m0 == 2 ? -1.f : 0.f);
        float curI = (m0 == 1) ? 1.f : (m0 == 3 ? -1.f : 0.f);
        double rs, rc;
        sincos(6.283185307179586 * ((double)k / 256.0), &rs, &rc);
        float rotR = (float)rc, rotI = (float)rs;
        const float2* xrow = (const float2*)buf;
        float yr = 0.f, yi = 0.f;
        #pragma unroll 8
        for (int j = s * 64; j < s * 64 + 64; ++j) {
            float2 x = xrow[j];   // broadcast
            yr = fmaf(x.x, curR, yr); yr = fmaf(-x.y, curI, yr);
            yi = fmaf(x.x, curI, yi); yi = fmaf( x.y, curR, yi);
            float nR = curR * rotR - curI * rotI;
            float nI = curR * rotI + curI * rotR;
            curR = nR; curI = nI;
        }
        ((float2*)(buf + 512))[tid] = make_float2(yr, yi);   // partA @512
    }
    __syncthreads();
    if (tid < 256) {
        const float2* pA = (const float2*)(buf + 512);
        float2 p0 = pA[tid], p1 = pA[tid+256], p2 = pA[tid+512], p3 = pA[tid+768];
        float Yr = p0.x + p1.x + p2.x + p3.x;
        float Yi = p0.y + p1.y + p2.y + p3.y;
        int mm = (l1 * tid) & 65535;
        float tv = (float)mm * (1.0f / 65536.0f);   // exact in fp32
        float twR = __builtin_amdgcn_cosf(tv);
        float twI = __builtin_amdgcn_sinf(tv);
        ((float2*)ZTf)[tid * 256 + l1] =
            make_float2(Yr * twR - Yi * twI, Yr * twI + Yi * twR);
    }
}

// ---------------------------------------------------------------------------
// Kernel 3: FFT stage B.  Block t1: out[t1+256*t2] = (1/L)*Re( sum_l1 Z[t1,l1]*W256^{l1*t2} ).
__global__ __launch_bounds__(1024) void k_fftB(
    const float* __restrict__ ZTf, float* __restrict__ out)
{
    __shared__ float2 zrow[256];
    __shared__ float partB[1024];
    int t1  = blockIdx.x;
    int tid = threadIdx.x;
    if (tid < 256) zrow[tid] = ((const float2*)ZTf)[t1 * 256 + tid];
    int k   = tid & 255;    // t2
    int s   = tid >> 8;
    int m0 = (s * k) & 3;
    float curR = (m0 == 0) ? 1.f : (m0 == 2 ? -1.f : 0.f);
    float curI = (m0 == 1) ? 1.f : (m0 == 3 ? -1.f : 0.f);
    double rs, rc;
    sincos(6.283185307179586 * ((double)k / 256.0), &rs, &rc);
    float rotR = (float)rc, rotI = (float)rs;
    __syncthreads();
    float o = 0.f;
    #pragma unroll 8
    for (int j = s * 64; j < s * 64 + 64; ++j) {
        float2 z = zrow[j];   // broadcast
        o = fmaf(z.x, curR, o);
        o = fmaf(-z.y, curI, o);
        float nR = curR * rotR - curI * rotI;
        float nI = curR * rotI + curI * rotR;
        curR = nR; curI = nI;
    }
    partB[tid] = o;
    __syncthreads();
    if (tid < 256) {
        float sum = partB[tid] + partB[tid+256] + partB[tid+512] + partB[tid+768];
        out[t1 + 256 * tid] = sum * (1.0f / 65536.0f);
    }
}

// ---------------------------------------------------------------------------
extern "C" void kernel_launch(void* const* d_in, const int* in_sizes, int n_in,
                              void* d_out, int out_size, void* d_ws, size_t ws_size,
                              hipStream_t stream)
{
    const float* Lambda_re = (const float*)d_in[0];
    const float* Lambda_im = (const float*)d_in[1];
    const float* p_re      = (const float*)d_in[2];
    const float* p_im      = (const float*)d_in[3];
    const float* q_re      = (const float*)d_in[4];
    const float* q_im      = (const float*)d_in[5];
    const float* Vc_re     = (const float*)d_in[6];
    const float* Vc_im     = (const float*)d_in[7];
    const float* Ct        = (const float*)d_in[8];
    const float* Bv        = (const float*)d_in[9];
    const float* log_step  = (const float*)d_in[10];

    float* wsf   = (float*)d_ws;
    float* terms = wsf + WS_TERMS;
    float* ZT    = wsf + WS_ZT;
    float* out   = (float*)d_out;

    k_setup<<<512, 256, 0, stream>>>(Lambda_re, Lambda_im, p_re, p_im, q_re, q_im,
                                     Vc_re, Vc_im, Ct, Bv, terms);
    k_mainA<<<256, 1024, 0, stream>>>(terms, log_step, ZT);
    k_fftB<<<256, 1024, 0, stream>>>(ZT, out);
}

// Round 5
// 109.086 us; speedup vs baseline: 1.0017x; 1.0017x over previous
//
#include <hip/hip_runtime.h>
#include <math.h>

// ws layout (floats):
//   terms: [0, 6144)        512 * 12 floats {Lr,Li, t0r,t0i, t1r,t1i, t2r,t2i, t3r,t3i, pad,pad}
//   ZT:    [8192, +131072)  65536 float2, stage-A output: ZT[t1*256 + l1]
constexpr int WS_TERMS = 0;
constexpr int WS_ZT    = 8192;

// ---------------------------------------------------------------------------
// Kernel 1: per-n setup.  Bc = Vc @ B (complex), terms[n] = {Lambda, a0*b0, a0*b1, a1*b0, a1*b1}
__global__ __launch_bounds__(256) void k_setup(
    const float* __restrict__ Lr, const float* __restrict__ Li,
    const float* __restrict__ pr, const float* __restrict__ pi,
    const float* __restrict__ qr, const float* __restrict__ qi,
    const float* __restrict__ Vr, const float* __restrict__ Vi,
    const float* __restrict__ Ct, const float* __restrict__ Bv,
    float* __restrict__ terms)
{
    __shared__ float red[8];
    int n = blockIdx.x;
    int t = threadIdx.x;
    float b0 = Bv[t], b1 = Bv[t + 256];
    float sr = fmaf(Vr[n*512 + t], b0, Vr[n*512 + t + 256] * b1);
    float si = fmaf(Vi[n*512 + t], b0, Vi[n*512 + t + 256] * b1);
    #pragma unroll
    for (int off = 32; off > 0; off >>= 1) {
        sr += __shfl_down(sr, off, 64);
        si += __shfl_down(si, off, 64);
    }
    if ((t & 63) == 0) { red[(t >> 6)*2] = sr; red[(t >> 6)*2 + 1] = si; }
    __syncthreads();
    if (t == 0) {
        float b0r = red[0] + red[2] + red[4] + red[6];
        float b0i = red[1] + red[3] + red[5] + red[7];
        float a0r = Ct[2*n], a0i = -Ct[2*n+1];   // conj(Ct_c)
        float a1r = qr[n],   a1i = -qi[n];       // conj(q)
        float b1r = pr[n],   b1i = pi[n];        // p
        float* tm = terms + n * 12;
        tm[0]  = Lr[n];                tm[1]  = Li[n];
        tm[2]  = a0r*b0r - a0i*b0i;    tm[3]  = a0r*b0i + a0i*b0r;
        tm[4]  = a0r*b1r - a0i*b1i;    tm[5]  = a0r*b1i + a0i*b1r;
        tm[6]  = a1r*b0r - a1i*b0i;    tm[7]  = a1r*b0i + a1i*b0r;
        tm[8]  = a1r*b1r - a1i*b1i;    tm[9]  = a1r*b1i + a1i*b1r;
        tm[10] = 0.f;                  tm[11] = 0.f;
    }
}

// ---------------------------------------------------------------------------
// Kernel 2 (fused): Cauchy reduction + resolvent + FFT stage A.
// Round-3 structure (proven 107 us): 256 blocks x 1024 threads; block = l1.
// Thread (u = tid&127, chunk = tid>>7): l2 in {u, u+128}, n in [chunk*64, chunk*64+64).
// NEW (r5): the h=0/h=1 pair is packed as float2 .x/.y so the SLP vectorizer can
// emit v_pk_fma_f32 / v_pk_mul_f32 (VOP3P packed fp32) -> ~half the VALU issue.
// Per-component expressions identical to r3 -> bit-identical results.
// LDS overlay (floats):
//   phase 1-2: terms[6144] @0
//   phase 3-4: part[4][256][9] @0 (9-pad), red[256][9] @9216
//   phase 5-6: xrow float2[256] @0, partA float2[1024] @512
__global__ __launch_bounds__(1024, 4) void k_mainA(
    const float* __restrict__ terms,
    const float* __restrict__ log_step,
    float* __restrict__ ZTf)
{
    __shared__ float buf[11520];   // 45 KB
    int tid = threadIdx.x;
    int l1  = blockIdx.x;

    // ---- stage terms -> LDS (1536 float4, coalesced)
    {
        float4* dst = (float4*)buf;
        const float4* src = (const float4*)terms;
        for (int i = tid; i < 1536; i += 1024) dst[i] = src[i];
    }

    int u     = tid & 127;
    int chunk = tid >> 7;          // wave-uniform

    // ---- per-l params for l = l1+256*u (h=0) and l+32768 (h=1), double precision.
    // Identical math to r3 (theta - pi*h); packed into float2 (.x = h0, .y = h1).
    double step = exp((double)log_step[0]);
    double t2s  = 2.0 / step;
    double th0  = -6.283185307179586 * ((double)(l1 + 256*u) / 65536.0);
    float2 gr2, gi2, cr2, ci2;
    {
        float gr[2], gi[2], cr_[2], ci_[2];
        #pragma unroll
        for (int h = 0; h < 2; ++h) {
            double th = th0 - 3.141592653589793 * (double)h;
            double sn, cn; sincos(th, &sn, &cn);
            double A = 1.0 - cn, C = 1.0 + cn, Bm = -sn, D = sn;
            double inv = 1.0 / (C*C + D*D);      // never 0 in double (incl. l = L/2)
            gr[h]  = (float)(t2s * (A*C + Bm*D) * inv);
            gi[h]  = (float)(t2s * (Bm*C - A*D) * inv);
            cr_[h] = (float)(2.0 * C * inv);
            ci_[h] = (float)(-2.0 * D * inv);
        }
        gr2 = make_float2(gr[0], gr[1]); gi2 = make_float2(gi[0], gi[1]);
        cr2 = make_float2(cr_[0], cr_[1]); ci2 = make_float2(ci_[0], ci_[1]);
    }
    __syncthreads();

    // ---- Cauchy loop: 64 n from LDS, h-pair packed as float2
    float2 ac[8];
    #pragma unroll
    for (int c = 0; c < 8; ++c) ac[c] = make_float2(0.f, 0.f);

    const float4* t4 = (const float4*)buf + chunk * 64 * 3;
    #pragma unroll 2
    for (int n = 0; n < 64; ++n) {
        float4 Aq = t4[n*3 + 0];   // Lr, Li, t0r, t0i  (broadcast ds_read_b128)
        float4 Bq = t4[n*3 + 1];   // t1r, t1i, t2r, t2i
        float4 Cq = t4[n*3 + 2];   // t3r, t3i, -, -
        float2 dr, di, dd, iv, rr, ri;
        dr.x = gr2.x - Aq.x;              dr.y = gr2.y - Aq.x;
        di.x = gi2.x - Aq.y;              di.y = gi2.y - Aq.y;
        dd.x = fmaf(dr.x, dr.x, di.x*di.x);
        dd.y = fmaf(dr.y, dr.y, di.y*di.y);      // inf at l=L/2 -> r=0 (validated)
        iv.x = __builtin_amdgcn_rcpf(dd.x);
        iv.y = __builtin_amdgcn_rcpf(dd.y);
        rr.x = dr.x * iv.x;               rr.y = dr.y * iv.y;
        ri.x = -di.x * iv.x;              ri.y = -di.y * iv.y;
        ac[0].x = fmaf(rr.x, Aq.z, ac[0].x);  ac[0].y = fmaf(rr.y, Aq.z, ac[0].y);
        ac[0].x = fmaf(-ri.x, Aq.w, ac[0].x); ac[0].y = fmaf(-ri.y, Aq.w, ac[0].y);
        ac[1].x = fmaf(rr.x, Aq.w, ac[1].x);  ac[1].y = fmaf(rr.y, Aq.w, ac[1].y);
        ac[1].x = fmaf( ri.x, Aq.z, ac[1].x); ac[1].y = fmaf( ri.y, Aq.z, ac[1].y);
        ac[2].x = fmaf(rr.x, Bq.x, ac[2].x);  ac[2].y = fmaf(rr.y, Bq.x, ac[2].y);
        ac[2].x = fmaf(-ri.x, Bq.y, ac[2].x); ac[2].y = fmaf(-ri.y, Bq.y, ac[2].y);
        ac[3].x = fmaf(rr.x, Bq.y, ac[3].x);  ac[3].y = fmaf(rr.y, Bq.y, ac[3].y);
        ac[3].x = fmaf( ri.x, Bq.x, ac[3].x); ac[3].y = fmaf( ri.y, Bq.x, ac[3].y);
        ac[4].x = fmaf(rr.x, Bq.z, ac[4].x);  ac[4].y = fmaf(rr.y, Bq.z, ac[4].y);
        ac[4].x = fmaf(-ri.x, Bq.w, ac[4].x); ac[4].y = fmaf(-ri.y, Bq.w, ac[4].y);
        ac[5].x = fmaf(rr.x, Bq.w, ac[5].x);  ac[5].y = fmaf(rr.y, Bq.w, ac[5].y);
        ac[5].x = fmaf( ri.x, Bq.z, ac[5].x); ac[5].y = fmaf( ri.y, Bq.z, ac[5].y);
        ac[6].x = fmaf(rr.x, Cq.x, ac[6].x);  ac[6].y = fmaf(rr.y, Cq.x, ac[6].y);
        ac[6].x = fmaf(-ri.x, Cq.y, ac[6].x); ac[6].y = fmaf(-ri.y, Cq.y, ac[6].y);
        ac[7].x = fmaf(rr.x, Cq.y, ac[7].x);  ac[7].y = fmaf(rr.y, Cq.y, ac[7].y);
        ac[7].x = fmaf( ri.x, Cq.x, ac[7].x); ac[7].y = fmaf( ri.y, Cq.x, ac[7].y);
    }
    __syncthreads();   // terms reads done; LDS reusable

    // ---- partials: chunks 4..7 write part[chunk-4][l2][c], then 0..3 accumulate (r3 scheme)
    if (chunk >= 4) {
        float* p0 = buf + (chunk - 4) * 2304 + u * 9;           // h=0 -> l2=u
        float* p1 = buf + (chunk - 4) * 2304 + (u + 128) * 9;   // h=1 -> l2=u+128
        #pragma unroll
        for (int c = 0; c < 8; ++c) { p0[c] = ac[c].x; p1[c] = ac[c].y; }
    }
    __syncthreads();
    if (chunk < 4) {
        float* p0 = buf + chunk * 2304 + u * 9;
        float* p1 = buf + chunk * 2304 + (u + 128) * 9;
        #pragma unroll
        for (int c = 0; c < 8; ++c) { p0[c] += ac[c].x; p1[c] += ac[c].y; }
    }
    __syncthreads();

    // ---- stage-1 reduce: 2048 slots (l2*8+c), sum 4 planes -> red @9216
    for (int s = tid; s < 2048; s += 1024) {
        int a = (s >> 3) * 9 + (s & 7);
        float v = buf[a] + buf[2304 + a] + buf[4608 + a] + buf[6912 + a];
        buf[9216 + a] = v;
    }
    __syncthreads();

    // ---- stage-2: atRoots for l2 = tid (tid<256); own params: h = tid>>7 (u = tid&127)
    if (tid < 256) {
        const float* rd = buf + 9216 + tid * 9;
        float s0r = rd[0], s0i = rd[1], s1r = rd[2], s1i = rd[3];
        float s2r = rd[4], s2i = rd[5], s3r = rd[6], s3i = rd[7];
        int h = tid >> 7;
        float crh = h ? cr2.y : cr2.x;
        float cih = h ? ci2.y : ci2.x;
        float e1r = 1.f + s3r, e1i = s3i;
        float eiv = 1.0f / fmaf(e1r, e1r, e1i * e1i);
        float m_r = s1r * s2r - s1i * s2i;
        float m_i = s1r * s2i + s1i * s2r;
        float q_r = (m_r * e1r + m_i * e1i) * eiv;
        float q_i = (m_i * e1r - m_r * e1i) * eiv;
        float u_r = s0r - q_r;
        float u_i = s0i - q_i;
        float at_r = crh * u_r - cih * u_i;
        float at_i = crh * u_i + cih * u_r;
        ((float2*)buf)[tid] = make_float2(at_r, at_i);   // xrow @0 (planes dead)
    }
    __syncthreads();

    // ---- FFT stage A over l2 (256-pt DFT, 4-way split) + W_L twiddle -> ZT
    // (y/cur packed float2; per-component expressions identical to r3)
    {
        int k = tid & 255;    // t1
        int s = tid >> 8;     // l2-chunk
        int m0 = (s * k) & 3;
        float2 cur;
        cur.x = (m0 == 0) ? 1.f : (m0 == 2 ? -1.f : 0.f);
        cur.y = (m0 == 1) ? 1.f : (m0 == 3 ? -1.f : 0.f);
        double rs, rc;
        sincos(6.283185307179586 * ((double)k / 256.0), &rs, &rc);
        float rotR = (float)rc, rotI = (float)rs;
        const float2* xrow = (const float2*)buf;
        float2 y = make_float2(0.f, 0.f);
        #pragma unroll 8
        for (int j = s * 64; j < s * 64 + 64; ++j) {
            float2 x = xrow[j];   // broadcast
            y.x = fmaf(x.x, cur.x, y.x);  y.y = fmaf(x.x, cur.y, y.y);
            y.x = fmaf(-x.y, cur.y, y.x); y.y = fmaf( x.y, cur.x, y.y);
            float nR = cur.x * rotR - cur.y * rotI;
            float nI = cur.x * rotI + cur.y * rotR;
            cur.x = nR; cur.y = nI;
        }
        ((float2*)(buf + 512))[tid] = y;   // partA @512
    }
    __syncthreads();
    if (tid < 256) {
        const float2* pA = (const float2*)(buf + 512);
        float2 p0 = pA[tid], p1 = pA[tid+256], p2 = pA[tid+512], p3 = pA[tid+768];
        float Yr = p0.x + p1.x + p2.x + p3.x;
        float Yi = p0.y + p1.y + p2.y + p3.y;
        int mm = (l1 * tid) & 65535;
        float tv = (float)mm * (1.0f / 65536.0f);   // exact in fp32
        float twR = __builtin_amdgcn_cosf(tv);
        float twI = __builtin_amdgcn_sinf(tv);
        ((float2*)ZTf)[tid * 256 + l1] =
            make_float2(Yr * twR - Yi * twI, Yr * twI + Yi * twR);
    }
}

// ---------------------------------------------------------------------------
// Kernel 3: FFT stage B.  Block t1: out[t1+256*t2] = (1/L)*Re( sum_l1 Z[t1,l1]*W256^{l1*t2} ).
__global__ __launch_bounds__(1024) void k_fftB(
    const float* __restrict__ ZTf, float* __restrict__ out)
{
    __shared__ float2 zrow[256];
    __shared__ float partB[1024];
    int t1  = blockIdx.x;
    int tid = threadIdx.x;
    if (tid < 256) zrow[tid] = ((const float2*)ZTf)[t1 * 256 + tid];
    int k   = tid & 255;    // t2
    int s   = tid >> 8;
    int m0 = (s * k) & 3;
    float curR = (m0 == 0) ? 1.f : (m0 == 2 ? -1.f : 0.f);
    float curI = (m0 == 1) ? 1.f : (m0 == 3 ? -1.f : 0.f);
    double rs, rc;
    sincos(6.283185307179586 * ((double)k / 256.0), &rs, &rc);
    float rotR = (float)rc, rotI = (float)rs;
    __syncthreads();
    float o = 0.f;
    #pragma unroll 8
    for (int j = s * 64; j < s * 64 + 64; ++j) {
        float2 z = zrow[j];   // broadcast
        o = fmaf(z.x, curR, o);
        o = fmaf(-z.y, curI, o);
        float nR = curR * rotR - curI * rotI;
        float nI = curR * rotI + curI * rotR;
        curR = nR; curI = nI;
    }
    partB[tid] = o;
    __syncthreads();
    if (tid < 256) {
        float sum = partB[tid] + partB[tid+256] + partB[tid+512] + partB[tid+768];
        out[t1 + 256 * tid] = sum * (1.0f / 65536.0f);
    }
}

// ---------------------------------------------------------------------------
extern "C" void kernel_launch(void* const* d_in, const int* in_sizes, int n_in,
                              void* d_out, int out_size, void* d_ws, size_t ws_size,
                              hipStream_t stream)
{
    const float* Lambda_re = (const float*)d_in[0];
    const float* Lambda_im = (const float*)d_in[1];
    const float* p_re      = (const float*)d_in[2];
    const float* p_im      = (const float*)d_in[3];
    const float* q_re      = (const float*)d_in[4];
    const float* q_im      = (const float*)d_in[5];
    const float* Vc_re     = (const float*)d_in[6];
    const float* Vc_im     = (const float*)d_in[7];
    const float* Ct        = (const float*)d_in[8];
    const float* Bv        = (const float*)d_in[9];
    const float* log_step  = (const float*)d_in[10];

    float* wsf   = (float*)d_ws;
    float* terms = wsf + WS_TERMS;
    float* ZT    = wsf + WS_ZT;
    float* out   = (float*)d_out;

    k_setup<<<512, 256, 0, stream>>>(Lambda_re, Lambda_im, p_re, p_im, q_re, q_im,
                                     Vc_re, Vc_im, Ct, Bv, terms);
    k_mainA<<<256, 1024, 0, stream>>>(terms, log_step, ZT);
    k_fftB<<<256, 1024, 0, stream>>>(ZT, out);
}